// Round 1
// baseline (166.107 us; speedup 1.0000x reference)
//
#include <hip/hip_runtime.h>

#define HH   1024
#define WW   1024
#define KS   15
#define PAD  7          // KS/2
#define CELL 256        // 1024/4
#define TILE 64         // output tile per block (64x64)
#define HALO (TILE + 2*PAD)   // 78
#define LSTR 84         // LDS row stride in floats (16B aligned, bank-balanced)

__global__ __launch_bounds__(256) void piecewise_blur_kernel(
    const float* __restrict__ x,
    const float* __restrict__ kern,
    float* __restrict__ out)
{
    __shared__ __align__(16) float s_tile[HALO * LSTR];
    __shared__ float s_k[KS * KS];
    __shared__ float s_inv;

    const int tid = threadIdx.x;
    const int tx0 = blockIdx.x * TILE;
    const int ty0 = blockIdx.y * TILE;
    const int bc  = blockIdx.z;            // b*c plane index (24 planes)

    const int ci = blockIdx.x >> 2;        // cell col (0..3)
    const int cj = blockIdx.y >> 2;        // cell row (0..3)
    const int cellx0 = ci * CELL, celly0 = cj * CELL;
    const int cellx1 = cellx0 + CELL - 1, celly1 = celly0 + CELL - 1;

    const float* plane = x + (size_t)bc * HH * WW;

    // ---- stage raw 15x15 kernel for this cell ----
    if (tid < KS * KS)
        s_k[tid] = kern[(cj * 4 + ci) * (KS * KS) + tid];

    // ---- stage 78x78 input halo with edge-clamp to CELL bounds ----
    for (int idx = tid; idx < HALO * HALO; idx += 256) {
        int rr = idx / HALO;
        int cc = idx - rr * HALO;
        int gy = ty0 + rr - PAD;
        int gx = tx0 + cc - PAD;
        gy = min(max(gy, celly0), celly1);
        gx = min(max(gx, cellx0), cellx1);
        s_tile[rr * LSTR + cc] = plane[gy * WW + gx];
    }
    __syncthreads();

    // ---- kernel-sum reduction on wave 0, broadcast 1/(sum+eps) ----
    if (tid < 64) {
        float s = 0.f;
        for (int i = tid; i < KS * KS; i += 64) s += s_k[i];
        #pragma unroll
        for (int m = 1; m < 64; m <<= 1) s += __shfl_xor(s, m, 64);
        if (tid == 0) s_inv = 1.0f / (s + 1e-12f);
    }
    __syncthreads();

    // ---- compute: each thread owns row r, cols [cq*16, cq*16+16) ----
    const int cq = tid & 3;
    const int r  = tid >> 2;               // 0..63
    const int colbase = cq * 16;

    float acc[16];
    #pragma unroll
    for (int o = 0; o < 16; ++o) acc[o] = 0.f;

    for (int dy = 0; dy < KS; ++dy) {
        const float* row = &s_tile[(r + dy) * LSTR + colbase];

        float rv[32];
        #pragma unroll
        for (int sg = 0; sg < 8; ++sg) {
            float4 v = *(const float4*)(row + sg * 4);   // ds_read_b128
            rv[sg * 4 + 0] = v.x;
            rv[sg * 4 + 1] = v.y;
            rv[sg * 4 + 2] = v.z;
            rv[sg * 4 + 3] = v.w;
        }

        float kr[KS];
        #pragma unroll
        for (int dx = 0; dx < KS; ++dx) kr[dx] = s_k[dy * KS + dx];

        #pragma unroll
        for (int dx = 0; dx < KS; ++dx) {
            #pragma unroll
            for (int o = 0; o < 16; ++o)
                acc[o] += kr[dx] * rv[o + dx];
        }
    }

    const float inv = s_inv;
    float* op = out + (size_t)bc * HH * WW + (size_t)(ty0 + r) * WW + tx0 + colbase;
    #pragma unroll
    for (int o = 0; o < 16; ++o) acc[o] *= inv;

    #pragma unroll
    for (int sg = 0; sg < 4; ++sg) {
        float4 v = make_float4(acc[sg * 4 + 0], acc[sg * 4 + 1],
                               acc[sg * 4 + 2], acc[sg * 4 + 3]);
        *(float4*)(op + sg * 4) = v;
    }
}

extern "C" void kernel_launch(void* const* d_in, const int* in_sizes, int n_in,
                              void* d_out, int out_size, void* d_ws, size_t ws_size,
                              hipStream_t stream) {
    (void)in_sizes; (void)n_in; (void)d_ws; (void)ws_size; (void)out_size;
    const float* x    = (const float*)d_in[0];
    const float* kern = (const float*)d_in[1];
    float* out        = (float*)d_out;

    dim3 grid(WW / TILE, HH / TILE, 8 * 3);   // 16 x 16 x 24
    piecewise_blur_kernel<<<grid, 256, 0, stream>>>(x, kern, out);
}

// Round 3
// 131.843 us; speedup vs baseline: 1.2599x; 1.2599x over previous
//
#include <hip/hip_runtime.h>

#define HH   1024
#define WW   1024
#define KS   15
#define PAD  7          // KS/2
#define CELL 256        // 1024/4
#define TILE 64         // output tile per block (64x64)
#define HALO (TILE + 2*PAD)   // 78
#define RW   88         // LDS row stride in f16 halves (176B: 16B-aligned, bank-floor for b128 reads)

typedef _Float16 half2v __attribute__((ext_vector_type(2)));

static __device__ __forceinline__ half2v as_h2(unsigned int u) {
    return __builtin_bit_cast(half2v, u);
}

__global__ __launch_bounds__(256, 4) void piecewise_blur_kernel(
    const float* __restrict__ x,
    const float* __restrict__ kern,
    float* __restrict__ out)
{
    __shared__ __align__(16) _Float16 s_tile[HALO * RW];       // 13728 B
    __shared__ __align__(16) unsigned int s_tapw[KS * 8];      // 480 B: half2 tap pairs, scale folded
    __shared__ float s_kraw[KS * KS];
    __shared__ float s_inv;

    const int tid = threadIdx.x;
    const int tx0 = blockIdx.x * TILE;
    const int ty0 = blockIdx.y * TILE;
    const int bc  = blockIdx.z;            // b*c plane index (24 planes)

    const int ci = blockIdx.x >> 2;        // cell col (0..3)
    const int cj = blockIdx.y >> 2;        // cell row (0..3)
    const int cellx0 = ci * CELL, celly0 = cj * CELL;
    const int cellx1 = cellx0 + CELL - 1, celly1 = celly0 + CELL - 1;

    const float* plane = x + (size_t)bc * HH * WW;

    // ---- stage raw 15x15 kernel (f32) ----
    if (tid < KS * KS)
        s_kraw[tid] = kern[(cj * 4 + ci) * (KS * KS) + tid];

    // ---- stage FULL 78x88 LDS footprint as f16 (pad cols clamp to edge) ----
    // Every half the compute phase can read is initialized deterministically.
    for (int idx = tid; idx < HALO * RW; idx += 256) {
        int rr = idx / RW;
        int cc = idx - rr * RW;
        int hc = min(cc, HALO - 1);        // pad cols 78..87 replicate col 77
        int gy = ty0 + rr - PAD;
        int gx = tx0 + hc - PAD;
        gy = min(max(gy, celly0), celly1);
        gx = min(max(gx, cellx0), cellx1);
        s_tile[rr * RW + cc] = (_Float16)plane[gy * WW + gx];
    }
    __syncthreads();

    // ---- kernel-sum reduction on wave 0 ----
    if (tid < 64) {
        float s = 0.f;
        for (int i = tid; i < KS * KS; i += 64) s += s_kraw[i];
        #pragma unroll
        for (int m = 1; m < 64; m <<= 1) s += __shfl_xor(s, m, 64);
        if (tid == 0) s_inv = 1.0f / (s + 1e-12f);
    }
    __syncthreads();

    // ---- build normalized f16 tap pairs: P[dy][p] = (k[2p], k[2p+1]) * inv, k[15]=0 ----
    if (tid < KS * 8) {
        const float inv = s_inv;
        int dy = tid >> 3;
        int p  = tid & 7;
        float a = s_kraw[dy * KS + 2 * p] * inv;
        float b = (2 * p + 1 < KS) ? s_kraw[dy * KS + 2 * p + 1] * inv : 0.f;
        half2v hp;
        hp.x = (_Float16)a;
        hp.y = (_Float16)b;
        s_tapw[tid] = __builtin_bit_cast(unsigned int, hp);
    }
    __syncthreads();

    // ---- compute: thread owns row r, cols [cq*16, cq*16+16) ----
    const int cq = tid & 3;
    const int r  = tid >> 2;               // 0..63
    const int colbase = cq * 16;

    float acc[16];
    #pragma unroll
    for (int o = 0; o < 16; ++o) acc[o] = 0.f;

    for (int dy = 0; dy < KS; ++dy) {
        // 32 halves = 16 words via 4 x ds_read_b128
        const uint4* rp = (const uint4*)(s_tile + (r + dy) * RW + colbase);
        unsigned int w[16];
        #pragma unroll
        for (int q = 0; q < 4; ++q) {
            uint4 v = rp[q];
            w[q * 4 + 0] = v.x; w[q * 4 + 1] = v.y;
            w[q * 4 + 2] = v.z; w[q * 4 + 3] = v.w;
        }

        // shifted words: sw[j] = (hi(w[j]), lo(w[j+1]))
        unsigned int sw[15];
        #pragma unroll
        for (int j = 0; j < 15; ++j)
            sw[j] = __builtin_amdgcn_alignbit(w[j + 1], w[j], 16);

        // tap pairs for this dy (broadcast reads)
        unsigned int tw[8];
        {
            const uint4* tp = (const uint4*)(s_tapw + dy * 8);
            uint4 t0 = tp[0], t1 = tp[1];
            tw[0] = t0.x; tw[1] = t0.y; tw[2] = t0.z; tw[3] = t0.w;
            tw[4] = t1.x; tw[5] = t1.y; tw[6] = t1.z; tw[7] = t1.w;
        }

        #pragma unroll
        for (int o = 0; o < 16; o += 2) {
            const int base = o >> 1;
            float a0 = acc[o];
            float a1 = acc[o + 1];
            #pragma unroll
            for (int p = 0; p < 8; ++p) {
                a0 = __builtin_amdgcn_fdot2(as_h2(w[base + p]),  as_h2(tw[p]), a0, false);
                a1 = __builtin_amdgcn_fdot2(as_h2(sw[base + p]), as_h2(tw[p]), a1, false);
            }
            acc[o]     = a0;
            acc[o + 1] = a1;
        }
    }

    float* op = out + (size_t)bc * HH * WW + (size_t)(ty0 + r) * WW + tx0 + colbase;
    #pragma unroll
    for (int sg = 0; sg < 4; ++sg) {
        float4 v = make_float4(acc[sg * 4 + 0], acc[sg * 4 + 1],
                               acc[sg * 4 + 2], acc[sg * 4 + 3]);
        *(float4*)(op + sg * 4) = v;
    }
}

extern "C" void kernel_launch(void* const* d_in, const int* in_sizes, int n_in,
                              void* d_out, int out_size, void* d_ws, size_t ws_size,
                              hipStream_t stream) {
    (void)in_sizes; (void)n_in; (void)d_ws; (void)ws_size; (void)out_size;
    const float* x    = (const float*)d_in[0];
    const float* kern = (const float*)d_in[1];
    float* out        = (float*)d_out;

    dim3 grid(WW / TILE, HH / TILE, 8 * 3);   // 16 x 16 x 24
    piecewise_blur_kernel<<<grid, 256, 0, stream>>>(x, kern, out);
}

// Round 4
// 89.252 us; speedup vs baseline: 1.8611x; 1.4772x over previous
//
#include <hip/hip_runtime.h>

#define HH    1024
#define WW    1024
#define KS    15
#define PAD   7
#define CELL  256
#define BX    64            // x-width per block (4 waves x 16)
#define TROWS 270           // staged rows: 256 + 2*PAD
#define TCOLS 80            // staged cols: [-7 .. 72] relative to bx0
#define NJP   16            // 16 row-patches of 16 rows = 256

typedef _Float16 f16x8 __attribute__((ext_vector_type(8)));
typedef float    f32x4 __attribute__((ext_vector_type(4)));

__global__ __launch_bounds__(256) void pb_mfma_kernel(
    const float* __restrict__ x,
    const float* __restrict__ kern,
    float* __restrict__ out)
{
    __shared__ __align__(16) _Float16 s_tile[TROWS * TCOLS];   // 43200 B
    __shared__ float s_kraw[KS * KS];
    __shared__ float s_inv;

    const int tid = threadIdx.x;
    const int bx0 = blockIdx.x * BX;       // global x of first output col
    const int ci  = blockIdx.x >> 2;       // cell col (4 strips per cell)
    const int cj  = blockIdx.y;            // cell row
    const int bc  = blockIdx.z;            // plane (b*c)

    const int cellx0 = ci * CELL, cellx1 = cellx0 + CELL - 1;
    const int celly0 = cj * CELL, celly1 = celly0 + CELL - 1;

    const float* plane = x + (size_t)bc * HH * WW;

    // ---- stage raw 15x15 kernel ----
    if (tid < KS * KS)
        s_kraw[tid] = kern[(cj * 4 + ci) * (KS * KS) + tid];

    // ---- stage 270x80 f16 halo strip, clamped to cell bounds ----
    for (int idx = tid; idx < TROWS * TCOLS; idx += 256) {
        int row = idx / TCOLS;
        int col = idx - row * TCOLS;
        int gy = min(max(celly0 + row - PAD, celly0), celly1);
        int gx = min(max(bx0 - PAD + col,   cellx0), cellx1);
        s_tile[idx] = (_Float16)plane[gy * WW + gx];
    }
    __syncthreads();

    // ---- kernel-sum reduction on wave 0 ----
    if (tid < 64) {
        float s = 0.f;
        for (int i = tid; i < KS * KS; i += 64) s += s_kraw[i];
        #pragma unroll
        for (int m = 1; m < 64; m <<= 1) s += __shfl_xor(s, m, 64);
        if (tid == 0) s_inv = 1.0f / (s + 1e-12f);
    }
    __syncthreads();

    const float inv = s_inv;
    const int lane = tid & 63;
    const int w    = tid >> 6;             // wave id: x sub-block
    const int g    = lane >> 4;            // k-group 0..3
    const int cc   = lane & 15;            // A-row / B-col / D-col index

    // ---- build Toeplitz A fragments, one per dy (scale folded) ----
    // A[i][k] = kh[dy][k-i] for k-i in [0,14], else 0.
    // Lane layout: i = lane&15, k = 8*(lane>>4)+e.
    f16x8 af[KS];
    #pragma unroll
    for (int dy = 0; dy < KS; ++dy) {
        f16x8 a;
        #pragma unroll
        for (int e = 0; e < 8; ++e) {
            int dx  = 8 * g + e - cc;
            int dxc = min(max(dx, 0), KS - 1);
            float kv = s_kraw[dy * KS + dxc] * inv;
            a[e] = (_Float16)((dx == dxc) ? kv : 0.f);
        }
        af[dy] = a;
    }

    // ---- main loop: 16 patches x 15 dy, fully unrolled ----
    // B[k][j]: lane reads image row (local) 16*jp+dy+cc, x-span k=8g..8g+7
    const _Float16* bbase = s_tile + cc * TCOLS + w * 16 + g * 8;
    float* oplane = out + (size_t)bc * HH * WW;

    #pragma unroll
    for (int jp = 0; jp < NJP; ++jp) {
        f32x4 acc0 = {0.f, 0.f, 0.f, 0.f};
        f32x4 acc1 = {0.f, 0.f, 0.f, 0.f};
        #pragma unroll
        for (int dy = 0; dy < KS; ++dy) {
            f16x8 b = *(const f16x8*)(bbase + (16 * jp + dy) * TCOLS);
            if (dy & 1)
                acc1 = __builtin_amdgcn_mfma_f32_16x16x32_f16(af[dy], b, acc1, 0, 0, 0);
            else
                acc0 = __builtin_amdgcn_mfma_f32_16x16x32_f16(af[dy], b, acc0, 0, 0, 0);
        }
        f32x4 r = acc0 + acc1;
        // D: col=lane&15 (image row), row=4*(lane>>4)+e (x position)
        float* op = oplane + (size_t)(celly0 + 16 * jp + cc) * WW + bx0 + 16 * w + 4 * g;
        *(f32x4*)op = r;
    }
}

extern "C" void kernel_launch(void* const* d_in, const int* in_sizes, int n_in,
                              void* d_out, int out_size, void* d_ws, size_t ws_size,
                              hipStream_t stream) {
    (void)in_sizes; (void)n_in; (void)d_ws; (void)ws_size; (void)out_size;
    const float* x    = (const float*)d_in[0];
    const float* kern = (const float*)d_in[1];
    float* out        = (float*)d_out;

    dim3 grid(WW / BX, 4, 8 * 3);   // 16 x-strips, 4 cell-rows, 24 planes
    pb_mfma_kernel<<<grid, 256, 0, stream>>>(x, kern, out);
}